// Round 15
// baseline (162.895 us; speedup 1.0000x reference)
//
#include <hip/hip_runtime.h>
#include <math.h>

#define NG 8
#define SEQ 4096
#define DM 1024
#define NE 64
#define GS (NG * SEQ)          // 32768 tokens
#define KSEL 1024              // expert capacity
#define MASK_ELEMS (NE * GS)   // 2097152
#define SEG 16
#define SEGLEN (GS / SEG)
#define CAP 2048               // max repair candidates per expert
#define CAP2 16384             // max compacted entries per expert (expect ~3.5K)
#define AST 40                 // A-plane LDS row stride in ushorts

typedef __attribute__((ext_vector_type(8))) short short8;
typedef __attribute__((ext_vector_type(4))) float f32x4;

__device__ __forceinline__ unsigned short f2bf(float v) {   // RN-even
  unsigned u = __float_as_uint(v);
  return (unsigned short)((u + 0x7FFFu + ((u >> 16) & 1u)) >> 16);
}
__device__ __forceinline__ float bf2f(unsigned short h) {
  return __uint_as_float(((unsigned)h) << 16);
}

// ---------------- Kernel 0: pre-split gate weights into 2 transposed bf16 planes --
__global__ __launch_bounds__(256)
void k_split(const float* __restrict__ w, unsigned short* __restrict__ wph,
             unsigned short* __restrict__ wpm) {
  const int t = blockIdx.x * 256 + threadIdx.x;
  const int k = t >> 6, e = t & 63;
  float v = w[t];
  unsigned short h = f2bf(v); float r = v - bf2f(h);
  const int o = e * 1024 + k;
  wph[o] = h; wpm[o] = f2bf(r);
}

// ---------------- Kernel 1: bf16x2 MFMA GEMM, K-split 2-wave blocks ---------------
// Block = 128 thr = 2 waves; 16 tokens. Wave w computes K in [w*512,(w+1)*512)
// (16 tiles of 32), wave-private LDS staging, NO barriers in the K loop ->
// 4096 waves total = 4 waves/SIMD (round-14: 2 waves/SIMD, latency-bound 85us).
// Partial sums meet in Lt[2][16][68]; one barrier; fused fp32 softmax.
__global__ __launch_bounds__(128, 4)
void k_gemm_softmax(const float* __restrict__ x,
                    const unsigned short* __restrict__ wph,
                    const unsigned short* __restrict__ wpm,
                    const float* __restrict__ bias, const float* __restrict__ temp,
                    float* __restrict__ probsT) {
  __shared__ __align__(16) unsigned short Ah[2][2][16 * AST], Am[2][2][16 * AST];
  __shared__ float Lt[2][16][68];
  float (*Pt)[20] = (float (*)[20])&Ah[0][0][0];   // overlay after loop (5120B ==)

  const int tid = threadIdx.x;
  const int w = tid >> 6, lane = tid & 63;
  const int lrow = lane & 15;          // A-row / B-col / D-col
  const int g = lane >> 4;             // k-slot group (8 k each)
  const int m0 = blockIdx.x * 16;
  const int t0 = w * 16;               // wave's first tile

  // --- probes: C/D (lane,reg)->(i,j) for mfma_f32_16x16x32_bf16 (exact ints) ---
  int irow[4], jcol[4];
  {
    union { unsigned short u[8]; short8 v; } ar, on;
#pragma unroll
    for (int j = 0; j < 8; ++j) { ar.u[j] = f2bf((float)lrow); on.u[j] = 0x3F80u; }
    f32x4 z = {0.f, 0.f, 0.f, 0.f};
    f32x4 p1 = __builtin_amdgcn_mfma_f32_16x16x32_bf16(ar.v, on.v, z, 0, 0, 0);
    f32x4 p2 = __builtin_amdgcn_mfma_f32_16x16x32_bf16(on.v, ar.v, z, 0, 0, 0);
#pragma unroll
    for (int b = 0; b < 4; ++b) {
      irow[b] = ((int)p1[b]) >> 5;
      jcol[b] = ((int)p2[b]) >> 5;
    }
  }

  f32x4 acc[4];
#pragma unroll
  for (int cb = 0; cb < 4; ++cb) acc[cb] = (f32x4){0.f, 0.f, 0.f, 0.f};

  f32x4 rA0, rA1;
  short8 bhA[4], bmA[4], bhB[4], bmB[4];
  const int arow = lane >> 2, af = lane & 3;
  const int aoff = arow * AST + af * 8;
  const int foff = lrow * AST + g * 8;
  const int boff = lrow * 1024 + g * 8;

#define LOADA(t)                                                                     \
  {                                                                                  \
    const float* ap = x + (size_t)(m0 + arow) * DM + (t) * 32 + af * 8;              \
    rA0 = __builtin_nontemporal_load((const f32x4*)ap);                              \
    rA1 = __builtin_nontemporal_load(((const f32x4*)ap) + 1);                        \
  }

#define SPLITA(bi)                                                                   \
  {                                                                                  \
    union { unsigned short u[8]; short8 v; } ph, pm;                                 \
    _Pragma("unroll")                                                                \
    for (int j = 0; j < 8; ++j) {                                                    \
      float v0 = (j < 4) ? rA0[j] : rA1[j - 4];                                      \
      unsigned short h_ = f2bf(v0); float r_ = v0 - bf2f(h_);                        \
      ph.u[j] = h_; pm.u[j] = f2bf(r_);                                              \
    }                                                                                \
    *(short8*)(&Ah[w][bi][aoff]) = ph.v;                                             \
    *(short8*)(&Am[w][bi][aoff]) = pm.v;                                             \
  }

#define LOADB(t, bh, bm)                                                             \
  {                                                                                  \
    _Pragma("unroll")                                                                \
    for (int cb = 0; cb < 4; ++cb) {                                                 \
      const size_t bo = (size_t)boff + cb * 16 * 1024 + (t) * 32;                    \
      bh[cb] = *(const short8*)(wph + bo);                                           \
      bm[cb] = *(const short8*)(wpm + bo);                                           \
    }                                                                                \
  }

#define MFMA_TILE(bi, bh, bm)                                                        \
  {                                                                                  \
    short8 ah_ = *(const short8*)(&Ah[w][bi][foff]);                                 \
    short8 am_ = *(const short8*)(&Am[w][bi][foff]);                                 \
    __builtin_amdgcn_s_setprio(1);                                                   \
    _Pragma("unroll")                                                                \
    for (int cb = 0; cb < 4; ++cb) {                                                 \
      acc[cb] = __builtin_amdgcn_mfma_f32_16x16x32_bf16(ah_, bh[cb], acc[cb], 0, 0, 0); \
      acc[cb] = __builtin_amdgcn_mfma_f32_16x16x32_bf16(am_, bh[cb], acc[cb], 0, 0, 0); \
      acc[cb] = __builtin_amdgcn_mfma_f32_16x16x32_bf16(ah_, bm[cb], acc[cb], 0, 0, 0); \
    }                                                                                \
    __builtin_amdgcn_s_setprio(0);                                                   \
  }

  LOADA(t0);
  SPLITA(0);
  LOADA(t0 + 1);
  LOADB(t0, bhA, bmA);

  for (int tt = 0; tt < 16; tt += 2) {
    LOADB(t0 + tt + 1, bhB, bmB);
    SPLITA(1);
    if (tt + 2 < 16) LOADA(t0 + tt + 2);
    MFMA_TILE(0, bhA, bmA);
    if (tt + 2 < 16) {
      LOADB(t0 + tt + 2, bhA, bmA);
      SPLITA(0);
      LOADA(t0 + tt + 3);
    }
    MFMA_TILE(1, bhB, bmB);
  }

#undef LOADA
#undef SPLITA
#undef LOADB
#undef MFMA_TILE

  // --- per-wave partial logits into Lt[w] via probe-measured mapping ---
#pragma unroll
  for (int cb = 0; cb < 4; ++cb)
#pragma unroll
    for (int b = 0; b < 4; ++b)
      Lt[w][irow[b]][cb * 16 + jcol[b]] = acc[cb][b];
  __syncthreads();

  // --- fused fp32 softmax: 8 threads per token, 8 experts each ---
  {
    float st = temp[0];
    if (st < 0.1f) st = 0.1f;
    const float inv_t = 1.0f / st;
    const int tk = tid >> 3, q = tid & 7;
    float l[8];
    float mx = -1.0e30f;
#pragma unroll
    for (int j = 0; j < 8; ++j) {
      const int e = q * 8 + j;
      l[j] = (Lt[0][tk][e] + Lt[1][tk][e] + bias[e]) * inv_t;
      mx = fmaxf(mx, l[j]);
    }
    mx = fmaxf(mx, __shfl_xor(mx, 1));
    mx = fmaxf(mx, __shfl_xor(mx, 2));
    mx = fmaxf(mx, __shfl_xor(mx, 4));
    float p[8], s = 0.0f;
#pragma unroll
    for (int j = 0; j < 8; ++j) { p[j] = __expf(l[j] - mx); s += p[j]; }
    s += __shfl_xor(s, 1);
    s += __shfl_xor(s, 2);
    s += __shfl_xor(s, 4);
    const float invs = 1.0f / s;
#pragma unroll
    for (int j = 0; j < 8; ++j) Pt[q * 8 + j][tk] = p[j] * invs;
  }
  __syncthreads();

  // --- expert-major store: 2 threads per expert, 8 floats each ---
  {
    const int e = tid >> 1, hf = tid & 1;
#pragma unroll
    for (int c2 = 0; c2 < 2; ++c2) {
      *(float4*)(probsT + (size_t)e * GS + m0 + hf * 8 + c2 * 4) =
          *(const float4*)(&Pt[e][hf * 8 + c2 * 4]);
    }
  }
}

// ------------- cooperative bucket pick from a 256-bin histogram (block-wide) ------
__device__ __forceinline__ void pick_scan(const unsigned* __restrict__ bins,
                                          unsigned r_in, unsigned& bucket,
                                          unsigned& r_out, unsigned* res) {
  __syncthreads();
  const int tid = threadIdx.x;
  if (tid < 64) {
    uint4 b = ((const uint4*)bins)[tid];
    unsigned s3 = b.w, s2 = b.z + s3, s1 = b.y + s2, s0 = b.x + s1;
    unsigned suf = s0;
#pragma unroll
    for (int off = 1; off < 64; off <<= 1) {
      unsigned t = __shfl_down(suf, off);
      if (tid + off < 64) suf += t;
    }
    unsigned above = suf - s0;
    unsigned inc0 = above + s0, inc1 = above + s1, inc2 = above + s2, inc3 = above + s3;
    if (inc3 >= r_in && inc3 - b.w < r_in) { res[0] = 4 * tid + 3; res[1] = r_in - (inc3 - b.w); }
    if (inc2 >= r_in && inc2 - b.z < r_in) { res[0] = 4 * tid + 2; res[1] = r_in - (inc2 - b.z); }
    if (inc1 >= r_in && inc1 - b.y < r_in) { res[0] = 4 * tid + 1; res[1] = r_in - (inc1 - b.y); }
    if (inc0 >= r_in && inc0 - b.x < r_in) { res[0] = 4 * tid + 0; res[1] = r_in - (inc0 - b.x); }
  }
  __syncthreads();
  bucket = res[0];
  r_out = res[1];
}

// ---------------- Kernel 2: pass-0 (top-byte) histogram, full scan ----------------
__global__ __launch_bounds__(256)
void k_hist0(const float* __restrict__ probsT, unsigned* __restrict__ ghist0) {
  __shared__ unsigned h[4][256];
  const int tid = threadIdx.x, wv = tid >> 6;
  const int e = blockIdx.x >> 4;
  const int seg = blockIdx.x & (SEG - 1);
  h[0][tid] = 0; h[1][tid] = 0; h[2][tid] = 0; h[3][tid] = 0;
  __syncthreads();
  const float4* col = (const float4*)(probsT + (size_t)e * GS + seg * SEGLEN);
#pragma unroll
  for (int i = 0; i < SEGLEN / 1024; ++i) {
    float4 v = col[i * 256 + tid];
    atomicAdd(&h[wv][__float_as_uint(v.x) >> 24], 1u);
    atomicAdd(&h[wv][__float_as_uint(v.y) >> 24], 1u);
    atomicAdd(&h[wv][__float_as_uint(v.z) >> 24], 1u);
    atomicAdd(&h[wv][__float_as_uint(v.w) >> 24], 1u);
  }
  __syncthreads();
  unsigned c = h[0][tid] + h[1][tid] + h[2][tid] + h[3][tid];
  if (c) atomicAdd(&ghist0[e * 256 + tid], c);
}

// ---------------- Kernel 3: compact tokens with top-byte >= b0-1 ------------------
// Superset proof: threshold T (1024th) has top-byte b0; window lo = T*(1-2e-3)
// can drop at most one top-byte bucket (byte spans a 4x value range). So the
// compacted list contains every definite (p>hi>T) and window (p>=lo) token.
__global__ __launch_bounds__(256)
void k_compact(const float* __restrict__ probsT, const unsigned* __restrict__ ghist0,
               unsigned* __restrict__ cCnt, int* __restrict__ cIdx,
               float* __restrict__ cKey) {
  __shared__ unsigned res[2];
  __shared__ unsigned locN, basePos;
  __shared__ int locIdx[2048];
  __shared__ float locKey[2048];
  const int tid = threadIdx.x;
  const int e = blockIdx.x >> 4;
  const int seg = blockIdx.x & (SEG - 1);

  if (tid == 0) locN = 0u;
  unsigned b0, r0;
  pick_scan(ghist0 + e * 256, KSEL, b0, r0, res);   // leading barrier covers init
  const unsigned blo = (b0 == 0u) ? 0u : (b0 - 1u);

  const float* col = probsT + (size_t)e * GS + seg * SEGLEN;
  for (int i = 0; i < SEGLEN / 256; ++i) {
    const int t = i * 256 + tid;
    const float p = col[t];
    if ((__float_as_uint(p) >> 24) >= blo) {
      unsigned pos = atomicAdd(&locN, 1u);
      locIdx[pos] = seg * SEGLEN + t;
      locKey[pos] = p;
    }
  }
  __syncthreads();
  if (tid == 0) basePos = locN ? atomicAdd(&cCnt[e], locN) : 0u;
  __syncthreads();
  const unsigned n = locN, bp = basePos;
  for (unsigned i = tid; i < n; i += 256) {
    const unsigned gp = bp + i;
    if (gp < CAP2) {
      cIdx[(size_t)e * CAP2 + gp] = locIdx[i];
      cKey[(size_t)e * CAP2 + gp] = locKey[i];
    }
  }
}

// ---------------- Kernel 4: per-expert radix passes 1-3 + classify ----------------
__global__ __launch_bounds__(256)
void k_select2(const unsigned* __restrict__ ghist0, const unsigned* __restrict__ cCnt,
               const int* __restrict__ cIdx, const float* __restrict__ cKey,
               const float* __restrict__ temp, unsigned* __restrict__ defCnt,
               int* __restrict__ defIdx, unsigned* __restrict__ candCnt,
               int* __restrict__ candIdx) {
  __shared__ unsigned res[2];
  __shared__ unsigned h[4][256];
  __shared__ unsigned hs[256];
  __shared__ unsigned nd, nc;
  const int tid = threadIdx.x, wv = tid >> 6;
  const int e = blockIdx.x;
  const int cnt = (int)min(cCnt[e], (unsigned)CAP2);

  unsigned b0, r;
  pick_scan(ghist0 + e * 256, KSEL, b0, r, res);
  unsigned pfx = b0 << 24;

  for (int pass = 1; pass < 4; ++pass) {
    const int shift = 24 - 8 * pass;
    const unsigned hm = 0xFFFFFFFFu << (shift + 8);
    for (int i = tid; i < 1024; i += 256) ((unsigned*)h)[i] = 0u;
    __syncthreads();
    for (int i = tid; i < cnt; i += 256) {
      unsigned key = __float_as_uint(cKey[(size_t)e * CAP2 + i]);
      if ((key & hm) == (pfx & hm)) atomicAdd(&h[wv][(key >> shift) & 255], 1u);
    }
    __syncthreads();
    hs[tid] = h[0][tid] + h[1][tid] + h[2][tid] + h[3][tid];
    unsigned b, rn;
    pick_scan(hs, r, b, rn, res);   // leading barrier covers hs writes
    pfx |= b << shift;
    r = rn;
  }

  const float thrv = __uint_as_float(pfx);
  float st = temp[0];
  if (st < 0.1f) st = 0.1f;
  const float rel = 2.0e-3f / st;
  const float hi = thrv * (1.0f + rel);
  const float lo = thrv * (1.0f - rel);

  if (tid == 0) { nd = 0u; nc = 0u; }
  __syncthreads();
  for (int i = tid; i < cnt; i += 256) {
    const float p = cKey[(size_t)e * CAP2 + i];
    const int t = cIdx[(size_t)e * CAP2 + i];
    if (p > hi) {
      unsigned pos = atomicAdd(&nd, 1u);
      if (pos < 1024u) defIdx[e * 1024 + pos] = t;
    } else if (p >= lo) {
      unsigned pos = atomicAdd(&nc, 1u);
      if (pos < CAP) candIdx[e * CAP + pos] = t;
    }
  }
  __syncthreads();
  if (tid == 0) {
    defCnt[e] = min(nd, 1024u);
    candCnt[e] = min(nc, (unsigned)CAP);
  }
}

// ---------------- Kernel 5: exact fp64 recompute of candidate probabilities -------
__global__ __launch_bounds__(256)
void k_repair(const float* __restrict__ x, const float* __restrict__ w,
              const float* __restrict__ bias, const float* __restrict__ temp,
              const unsigned* __restrict__ candCnt, const int* __restrict__ candIdx,
              double* __restrict__ candKey) {
  __shared__ double red[4][64];
  const int e = blockIdx.x >> 4;
  const int chunk = blockIdx.x & 15;
  const int tid = threadIdx.x;
  const int ee = tid & 63, q = tid >> 6;
  const int cnt = (int)min(candCnt[e], (unsigned)CAP);

  double st = (double)temp[0];
  if (st < 0.1) st = 0.1;
  const double inv_t = 1.0 / st;

  for (int i = chunk; i < cnt; i += 16) {
    const int t = candIdx[e * CAP + i];
    const float* xr = x + (size_t)t * DM;
    double s0 = 0.0, s1 = 0.0, s2 = 0.0, s3 = 0.0;
    const int kb = q * 256;
    for (int k = kb; k < kb + 256; k += 4) {
      s0 += (double)xr[k + 0] * (double)w[(size_t)(k + 0) * NE + ee];
      s1 += (double)xr[k + 1] * (double)w[(size_t)(k + 1) * NE + ee];
      s2 += (double)xr[k + 2] * (double)w[(size_t)(k + 2) * NE + ee];
      s3 += (double)xr[k + 3] * (double)w[(size_t)(k + 3) * NE + ee];
    }
    red[q][ee] = (s0 + s1) + (s2 + s3);
    __syncthreads();
    if (tid < 64) {
      double l = (red[0][tid] + red[1][tid] + red[2][tid] + red[3][tid] +
                  (double)bias[tid]) * inv_t;
      double m = l;
#pragma unroll
      for (int off = 1; off < 64; off <<= 1) m = fmax(m, __shfl_xor(m, off));
      double ex = exp(l - m);
      double ss = ex;
#pragma unroll
      for (int off = 1; off < 64; off <<= 1) ss += __shfl_xor(ss, off);
      if (tid == e) candKey[e * CAP + i] = ex / ss;
    }
    __syncthreads();
  }
}

// ---------------- Kernel 6: rank candidates + sparse output (out pre-zeroed) ------
__global__ __launch_bounds__(256)
void k_finish(const unsigned* __restrict__ defCnt, const int* __restrict__ defIdx,
              const unsigned* __restrict__ candCnt, const int* __restrict__ candIdx,
              const double* __restrict__ candKey, const float* __restrict__ probsT,
              float* __restrict__ out) {
  __shared__ double kd[CAP];
  __shared__ int ti[CAP];
  const int e = blockIdx.x, tid = threadIdx.x;
  const int nd = (int)defCnt[e];
  const int cnt = (int)min(candCnt[e], (unsigned)CAP);
  const int need = KSEL - nd;

  for (int i = tid; i < nd; i += 256) {
    const int t = defIdx[e * 1024 + i];
    out[(size_t)e * GS + t] = 1.0f;
    out[(size_t)MASK_ELEMS + (size_t)e * GS + t] = probsT[(size_t)e * GS + t];
  }
  for (int i = tid; i < cnt; i += 256) {
    kd[i] = candKey[e * CAP + i];
    ti[i] = candIdx[e * CAP + i];
  }
  __syncthreads();
  for (int i = tid; i < cnt; i += 256) {
    const double ki = kd[i];
    const int tii = ti[i];
    int rank = 0;
    for (int j = 0; j < cnt; ++j)
      rank += (kd[j] > ki) || (kd[j] == ki && ti[j] < tii);
    if (rank < need) {
      out[(size_t)e * GS + tii] = 1.0f;
      out[(size_t)MASK_ELEMS + (size_t)e * GS + tii] = probsT[(size_t)e * GS + tii];
    }
  }
}

extern "C" void kernel_launch(void* const* d_in, const int* in_sizes, int n_in,
                              void* d_out, int out_size, void* d_ws, size_t ws_size,
                              hipStream_t stream) {
  const float* x    = (const float*)d_in[0];
  const float* gw   = (const float*)d_in[1];
  const float* gb   = (const float*)d_in[2];
  const float* temp = (const float*)d_in[3];

  float* probsT    = (float*)d_ws;                                        // 8MB
  unsigned* ghist0 = (unsigned*)((char*)d_ws + (size_t)MASK_ELEMS * 4);   // 64KB
  unsigned* cCnt   = ghist0 + NE * 256;                                   // 256B
  unsigned* defCnt = cCnt + NE;                                           // 256B
  unsigned* candCnt = defCnt + NE;                                        // 256B
  int* defIdx      = (int*)(candCnt + NE);                                // 256KB
  int* candIdx     = defIdx + NE * 1024;                                  // 512KB
  double* candKey  = (double*)(candIdx + NE * CAP);                       // 1MB
  int* cIdx        = (int*)(candKey + NE * CAP);                          // 4MB
  float* cKey      = (float*)(cIdx + (size_t)NE * CAP2);                  // 4MB
  unsigned short* wph = (unsigned short*)(cKey + (size_t)NE * CAP2);      // 128KB
  unsigned short* wpm = wph + DM * NE;                                    // 128KB

  hipMemsetAsync(ghist0, 0, (NE * 256 + NE) * sizeof(unsigned), stream);
  hipMemsetAsync(d_out, 0, (size_t)out_size * sizeof(float), stream);
  k_split<<<DM * NE / 256, 256, 0, stream>>>(gw, wph, wpm);
  k_gemm_softmax<<<GS / 16, 128, 0, stream>>>(x, wph, wpm, gb, temp, probsT);
  k_hist0<<<NE * SEG, 256, 0, stream>>>(probsT, ghist0);
  k_compact<<<NE * SEG, 256, 0, stream>>>(probsT, ghist0, cCnt, cIdx, cKey);
  k_select2<<<NE, 256, 0, stream>>>(ghist0, cCnt, cIdx, cKey, temp, defCnt,
                                    defIdx, candCnt, candIdx);
  k_repair<<<NE * 16, 256, 0, stream>>>(x, gw, gb, temp, candCnt, candIdx, candKey);
  k_finish<<<NE, 256, 0, stream>>>(defCnt, defIdx, candCnt, candIdx, candKey,
                                   probsT, (float*)d_out);
}

// Round 16
// 143.386 us; speedup vs baseline: 1.1361x; 1.1361x over previous
//
#include <hip/hip_runtime.h>
#include <math.h>

#define NG 8
#define SEQ 4096
#define DM 1024
#define NE 64
#define GS (NG * SEQ)          // 32768 tokens
#define KSEL 1024              // expert capacity
#define MASK_ELEMS (NE * GS)   // 2097152
#define SEG 16
#define SEGLEN (GS / SEG)
#define CAP 2048               // max repair candidates per expert
#define CAP2 16384             // max compacted entries per expert
#define AST 40                 // A-plane LDS row stride in ushorts

typedef __attribute__((ext_vector_type(8))) short short8;
typedef __attribute__((ext_vector_type(4))) float f32x4;

__device__ __forceinline__ unsigned short f2bf(float v) {   // RN-even
  unsigned u = __float_as_uint(v);
  return (unsigned short)((u + 0x7FFFu + ((u >> 16) & 1u)) >> 16);
}
__device__ __forceinline__ float bf2f(unsigned short h) {
  return __uint_as_float(((unsigned)h) << 16);
}

// ---------------- Kernel 0: pre-split gate weights, WAVE-FRAGMENT-ORDER layout ----
// Round-15 lesson: [e][k] planes made LOADB stride-2KB per lane -> 64 cache lines
// per instr -> 4.3GB L2 traffic -> gemm pinned at ~87us regardless of occupancy.
// New layout: element (k,e) -> (tile*4+cb)*512 + (g*16+lrow)*8 + j, so one wave's
// (tile,cb) B-fragment load is 64 lanes x 16B CONTIGUOUS (1KB, 8 lines).
__global__ __launch_bounds__(256)
void k_split(const float* __restrict__ w, unsigned short* __restrict__ wph,
             unsigned short* __restrict__ wpm) {
  const int t = blockIdx.x * 256 + threadIdx.x;
  const int k = t >> 6, e = t & 63;
  float v = w[t];
  unsigned short h = f2bf(v); float r = v - bf2f(h);
  const int tile = k >> 5, g = (k >> 3) & 3, j = k & 7;
  const int cb = e >> 4, lrow = e & 15;
  const size_t o = (size_t)(tile * 4 + cb) * 512 + (g * 16 + lrow) * 8 + j;
  wph[o] = h; wpm[o] = f2bf(r);
}

// ---------------- Kernel 1: bf16x2 MFMA GEMM, K-split 2-wave blocks ---------------
__global__ __launch_bounds__(128, 4)
void k_gemm_softmax(const float* __restrict__ x,
                    const unsigned short* __restrict__ wph,
                    const unsigned short* __restrict__ wpm,
                    const float* __restrict__ bias, const float* __restrict__ temp,
                    float* __restrict__ probsT) {
  __shared__ __align__(16) unsigned short Ah[2][2][16 * AST], Am[2][2][16 * AST];
  __shared__ float Lt[2][16][68];
  float (*Pt)[20] = (float (*)[20])&Ah[0][0][0];   // overlay after loop

  const int tid = threadIdx.x;
  const int w = tid >> 6, lane = tid & 63;
  const int lrow = lane & 15;          // A-row / B-col / D-col
  const int g = lane >> 4;             // k-slot group (8 k each)
  const int m0 = blockIdx.x * 16;
  const int t0 = w * 16;               // wave's first tile

  // --- probes: C/D (lane,reg)->(i,j) for mfma_f32_16x16x32_bf16 (exact ints) ---
  int irow[4], jcol[4];
  {
    union { unsigned short u[8]; short8 v; } ar, on;
#pragma unroll
    for (int j = 0; j < 8; ++j) { ar.u[j] = f2bf((float)lrow); on.u[j] = 0x3F80u; }
    f32x4 z = {0.f, 0.f, 0.f, 0.f};
    f32x4 p1 = __builtin_amdgcn_mfma_f32_16x16x32_bf16(ar.v, on.v, z, 0, 0, 0);
    f32x4 p2 = __builtin_amdgcn_mfma_f32_16x16x32_bf16(on.v, ar.v, z, 0, 0, 0);
#pragma unroll
    for (int b = 0; b < 4; ++b) {
      irow[b] = ((int)p1[b]) >> 5;
      jcol[b] = ((int)p2[b]) >> 5;
    }
  }

  f32x4 acc[4];
#pragma unroll
  for (int cb = 0; cb < 4; ++cb) acc[cb] = (f32x4){0.f, 0.f, 0.f, 0.f};

  f32x4 rA0, rA1;
  short8 bhA[4], bmA[4], bhB[4], bmB[4];
  const int arow = lane >> 2, af = lane & 3;
  const int aoff = arow * AST + af * 8;
  const int foff = lrow * AST + g * 8;
  const int boff = lane * 8;           // contiguous fragment within (tile,cb) chunk

#define LOADA(t)                                                                     \
  {                                                                                  \
    const float* ap = x + (size_t)(m0 + arow) * DM + (t) * 32 + af * 8;              \
    rA0 = __builtin_nontemporal_load((const f32x4*)ap);                              \
    rA1 = __builtin_nontemporal_load(((const f32x4*)ap) + 1);                        \
  }

#define SPLITA(bi)                                                                   \
  {                                                                                  \
    union { unsigned short u[8]; short8 v; } ph, pm;                                 \
    _Pragma("unroll")                                                                \
    for (int j = 0; j < 8; ++j) {                                                    \
      float v0 = (j < 4) ? rA0[j] : rA1[j - 4];                                      \
      unsigned short h_ = f2bf(v0); float r_ = v0 - bf2f(h_);                        \
      ph.u[j] = h_; pm.u[j] = f2bf(r_);                                              \
    }                                                                                \
    *(short8*)(&Ah[w][bi][aoff]) = ph.v;                                             \
    *(short8*)(&Am[w][bi][aoff]) = pm.v;                                             \
  }

#define LOADB(t, bh, bm)                                                             \
  {                                                                                  \
    _Pragma("unroll")                                                                \
    for (int cb = 0; cb < 4; ++cb) {                                                 \
      const size_t bo = (size_t)((t) * 4 + cb) * 512 + boff;                         \
      bh[cb] = *(const short8*)(wph + bo);                                           \
      bm[cb] = *(const short8*)(wpm + bo);                                           \
    }                                                                                \
  }

#define MFMA_TILE(bi, bh, bm)                                                        \
  {                                                                                  \
    short8 ah_ = *(const short8*)(&Ah[w][bi][foff]);                                 \
    short8 am_ = *(const short8*)(&Am[w][bi][foff]);                                 \
    __builtin_amdgcn_s_setprio(1);                                                   \
    _Pragma("unroll")                                                                \
    for (int cb = 0; cb < 4; ++cb) {                                                 \
      acc[cb] = __builtin_amdgcn_mfma_f32_16x16x32_bf16(ah_, bh[cb], acc[cb], 0, 0, 0); \
      acc[cb] = __builtin_amdgcn_mfma_f32_16x16x32_bf16(am_, bh[cb], acc[cb], 0, 0, 0); \
      acc[cb] = __builtin_amdgcn_mfma_f32_16x16x32_bf16(ah_, bm[cb], acc[cb], 0, 0, 0); \
    }                                                                                \
    __builtin_amdgcn_s_setprio(0);                                                   \
  }

  LOADA(t0);
  SPLITA(0);
  LOADA(t0 + 1);
  LOADB(t0, bhA, bmA);

  for (int tt = 0; tt < 16; tt += 2) {
    LOADB(t0 + tt + 1, bhB, bmB);
    SPLITA(1);
    if (tt + 2 < 16) LOADA(t0 + tt + 2);
    MFMA_TILE(0, bhA, bmA);
    if (tt + 2 < 16) {
      LOADB(t0 + tt + 2, bhA, bmA);
      SPLITA(0);
      LOADA(t0 + tt + 3);
    }
    MFMA_TILE(1, bhB, bmB);
  }

#undef LOADA
#undef SPLITA
#undef LOADB
#undef MFMA_TILE

  // --- per-wave partial logits into Lt[w] via probe-measured mapping ---
#pragma unroll
  for (int cb = 0; cb < 4; ++cb)
#pragma unroll
    for (int b = 0; b < 4; ++b)
      Lt[w][irow[b]][cb * 16 + jcol[b]] = acc[cb][b];
  __syncthreads();

  // --- fused fp32 softmax: 8 threads per token, 8 experts each ---
  {
    float st = temp[0];
    if (st < 0.1f) st = 0.1f;
    const float inv_t = 1.0f / st;
    const int tk = tid >> 3, q = tid & 7;
    float l[8];
    float mx = -1.0e30f;
#pragma unroll
    for (int j = 0; j < 8; ++j) {
      const int e = q * 8 + j;
      l[j] = (Lt[0][tk][e] + Lt[1][tk][e] + bias[e]) * inv_t;
      mx = fmaxf(mx, l[j]);
    }
    mx = fmaxf(mx, __shfl_xor(mx, 1));
    mx = fmaxf(mx, __shfl_xor(mx, 2));
    mx = fmaxf(mx, __shfl_xor(mx, 4));
    float p[8], s = 0.0f;
#pragma unroll
    for (int j = 0; j < 8; ++j) { p[j] = __expf(l[j] - mx); s += p[j]; }
    s += __shfl_xor(s, 1);
    s += __shfl_xor(s, 2);
    s += __shfl_xor(s, 4);
    const float invs = 1.0f / s;
#pragma unroll
    for (int j = 0; j < 8; ++j) Pt[q * 8 + j][tk] = p[j] * invs;
  }
  __syncthreads();

  // --- expert-major store: 2 threads per expert, 8 floats each ---
  {
    const int e = tid >> 1, hf = tid & 1;
#pragma unroll
    for (int c2 = 0; c2 < 2; ++c2) {
      *(float4*)(probsT + (size_t)e * GS + m0 + hf * 8 + c2 * 4) =
          *(const float4*)(&Pt[e][hf * 8 + c2 * 4]);
    }
  }
}

// ------------- cooperative bucket pick from a 256-bin histogram (block-wide) ------
__device__ __forceinline__ void pick_scan(const unsigned* __restrict__ bins,
                                          unsigned r_in, unsigned& bucket,
                                          unsigned& r_out, unsigned* res) {
  __syncthreads();
  const int tid = threadIdx.x;
  if (tid < 64) {
    uint4 b = ((const uint4*)bins)[tid];
    unsigned s3 = b.w, s2 = b.z + s3, s1 = b.y + s2, s0 = b.x + s1;
    unsigned suf = s0;
#pragma unroll
    for (int off = 1; off < 64; off <<= 1) {
      unsigned t = __shfl_down(suf, off);
      if (tid + off < 64) suf += t;
    }
    unsigned above = suf - s0;
    unsigned inc0 = above + s0, inc1 = above + s1, inc2 = above + s2, inc3 = above + s3;
    if (inc3 >= r_in && inc3 - b.w < r_in) { res[0] = 4 * tid + 3; res[1] = r_in - (inc3 - b.w); }
    if (inc2 >= r_in && inc2 - b.z < r_in) { res[0] = 4 * tid + 2; res[1] = r_in - (inc2 - b.z); }
    if (inc1 >= r_in && inc1 - b.y < r_in) { res[0] = 4 * tid + 1; res[1] = r_in - (inc1 - b.y); }
    if (inc0 >= r_in && inc0 - b.x < r_in) { res[0] = 4 * tid + 0; res[1] = r_in - (inc0 - b.x); }
  }
  __syncthreads();
  bucket = res[0];
  r_out = res[1];
}

// ---------------- Kernel 2: pass-0 (top-byte) histogram, full scan ----------------
__global__ __launch_bounds__(256)
void k_hist0(const float* __restrict__ probsT, unsigned* __restrict__ ghist0) {
  __shared__ unsigned h[4][256];
  const int tid = threadIdx.x, wv = tid >> 6;
  const int e = blockIdx.x >> 4;
  const int seg = blockIdx.x & (SEG - 1);
  h[0][tid] = 0; h[1][tid] = 0; h[2][tid] = 0; h[3][tid] = 0;
  __syncthreads();
  const float4* col = (const float4*)(probsT + (size_t)e * GS + seg * SEGLEN);
#pragma unroll
  for (int i = 0; i < SEGLEN / 1024; ++i) {
    float4 v = col[i * 256 + tid];
    atomicAdd(&h[wv][__float_as_uint(v.x) >> 24], 1u);
    atomicAdd(&h[wv][__float_as_uint(v.y) >> 24], 1u);
    atomicAdd(&h[wv][__float_as_uint(v.z) >> 24], 1u);
    atomicAdd(&h[wv][__float_as_uint(v.w) >> 24], 1u);
  }
  __syncthreads();
  unsigned c = h[0][tid] + h[1][tid] + h[2][tid] + h[3][tid];
  if (c) atomicAdd(&ghist0[e * 256 + tid], c);
}

// ---------------- Kernel 3: compact tokens with top-byte >= b0-1 ------------------
__global__ __launch_bounds__(256)
void k_compact(const float* __restrict__ probsT, const unsigned* __restrict__ ghist0,
               unsigned* __restrict__ cCnt, int* __restrict__ cIdx,
               float* __restrict__ cKey) {
  __shared__ unsigned res[2];
  __shared__ unsigned locN, basePos;
  __shared__ int locIdx[2048];
  __shared__ float locKey[2048];
  const int tid = threadIdx.x;
  const int e = blockIdx.x >> 4;
  const int seg = blockIdx.x & (SEG - 1);

  if (tid == 0) locN = 0u;
  unsigned b0, r0;
  pick_scan(ghist0 + e * 256, KSEL, b0, r0, res);   // leading barrier covers init
  const unsigned blo = (b0 == 0u) ? 0u : (b0 - 1u);

  const float* col = probsT + (size_t)e * GS + seg * SEGLEN;
  for (int i = 0; i < SEGLEN / 256; ++i) {
    const int t = i * 256 + tid;
    const float p = col[t];
    if ((__float_as_uint(p) >> 24) >= blo) {
      unsigned pos = atomicAdd(&locN, 1u);
      locIdx[pos] = seg * SEGLEN + t;
      locKey[pos] = p;
    }
  }
  __syncthreads();
  if (tid == 0) basePos = locN ? atomicAdd(&cCnt[e], locN) : 0u;
  __syncthreads();
  const unsigned n = locN, bp = basePos;
  for (unsigned i = tid; i < n; i += 256) {
    const unsigned gp = bp + i;
    if (gp < CAP2) {
      cIdx[(size_t)e * CAP2 + gp] = locIdx[i];
      cKey[(size_t)e * CAP2 + gp] = locKey[i];
    }
  }
}

// ---------------- Kernel 4: per-expert radix passes 1-3 + classify ----------------
__global__ __launch_bounds__(256)
void k_select2(const unsigned* __restrict__ ghist0, const unsigned* __restrict__ cCnt,
               const int* __restrict__ cIdx, const float* __restrict__ cKey,
               const float* __restrict__ temp, unsigned* __restrict__ defCnt,
               int* __restrict__ defIdx, unsigned* __restrict__ candCnt,
               int* __restrict__ candIdx) {
  __shared__ unsigned res[2];
  __shared__ unsigned h[4][256];
  __shared__ unsigned hs[256];
  __shared__ unsigned nd, nc;
  const int tid = threadIdx.x, wv = tid >> 6;
  const int e = blockIdx.x;
  const int cnt = (int)min(cCnt[e], (unsigned)CAP2);

  unsigned b0, r;
  pick_scan(ghist0 + e * 256, KSEL, b0, r, res);
  unsigned pfx = b0 << 24;

  for (int pass = 1; pass < 4; ++pass) {
    const int shift = 24 - 8 * pass;
    const unsigned hm = 0xFFFFFFFFu << (shift + 8);
    for (int i = tid; i < 1024; i += 256) ((unsigned*)h)[i] = 0u;
    __syncthreads();
    for (int i = tid; i < cnt; i += 256) {
      unsigned key = __float_as_uint(cKey[(size_t)e * CAP2 + i]);
      if ((key & hm) == (pfx & hm)) atomicAdd(&h[wv][(key >> shift) & 255], 1u);
    }
    __syncthreads();
    hs[tid] = h[0][tid] + h[1][tid] + h[2][tid] + h[3][tid];
    unsigned b, rn;
    pick_scan(hs, r, b, rn, res);
    pfx |= b << shift;
    r = rn;
  }

  const float thrv = __uint_as_float(pfx);
  float st = temp[0];
  if (st < 0.1f) st = 0.1f;
  const float rel = 2.0e-3f / st;
  const float hi = thrv * (1.0f + rel);
  const float lo = thrv * (1.0f - rel);

  if (tid == 0) { nd = 0u; nc = 0u; }
  __syncthreads();
  for (int i = tid; i < cnt; i += 256) {
    const float p = cKey[(size_t)e * CAP2 + i];
    const int t = cIdx[(size_t)e * CAP2 + i];
    if (p > hi) {
      unsigned pos = atomicAdd(&nd, 1u);
      if (pos < 1024u) defIdx[e * 1024 + pos] = t;
    } else if (p >= lo) {
      unsigned pos = atomicAdd(&nc, 1u);
      if (pos < CAP) candIdx[e * CAP + pos] = t;
    }
  }
  __syncthreads();
  if (tid == 0) {
    defCnt[e] = min(nd, 1024u);
    candCnt[e] = min(nc, (unsigned)CAP);
  }
}

// ---------------- Kernel 5: exact fp64 recompute of candidate probabilities -------
__global__ __launch_bounds__(256)
void k_repair(const float* __restrict__ x, const float* __restrict__ w,
              const float* __restrict__ bias, const float* __restrict__ temp,
              const unsigned* __restrict__ candCnt, const int* __restrict__ candIdx,
              double* __restrict__ candKey) {
  __shared__ double red[4][64];
  const int e = blockIdx.x >> 4;
  const int chunk = blockIdx.x & 15;
  const int tid = threadIdx.x;
  const int ee = tid & 63, q = tid >> 6;
  const int cnt = (int)min(candCnt[e], (unsigned)CAP);

  double st = (double)temp[0];
  if (st < 0.1) st = 0.1;
  const double inv_t = 1.0 / st;

  for (int i = chunk; i < cnt; i += 16) {
    const int t = candIdx[e * CAP + i];
    const float* xr = x + (size_t)t * DM;
    double s0 = 0.0, s1 = 0.0, s2 = 0.0, s3 = 0.0;
    const int kb = q * 256;
    for (int k = kb; k < kb + 256; k += 4) {
      s0 += (double)xr[k + 0] * (double)w[(size_t)(k + 0) * NE + ee];
      s1 += (double)xr[k + 1] * (double)w[(size_t)(k + 1) * NE + ee];
      s2 += (double)xr[k + 2] * (double)w[(size_t)(k + 2) * NE + ee];
      s3 += (double)xr[k + 3] * (double)w[(size_t)(k + 3) * NE + ee];
    }
    red[q][ee] = (s0 + s1) + (s2 + s3);
    __syncthreads();
    if (tid < 64) {
      double l = (red[0][tid] + red[1][tid] + red[2][tid] + red[3][tid] +
                  (double)bias[tid]) * inv_t;
      double m = l;
#pragma unroll
      for (int off = 1; off < 64; off <<= 1) m = fmax(m, __shfl_xor(m, off));
      double ex = exp(l - m);
      double ss = ex;
#pragma unroll
      for (int off = 1; off < 64; off <<= 1) ss += __shfl_xor(ss, off);
      if (tid == e) candKey[e * CAP + i] = ex / ss;
    }
    __syncthreads();
  }
}

// ---------------- Kernel 6: rank candidates + sparse output (out pre-zeroed) ------
__global__ __launch_bounds__(256)
void k_finish(const unsigned* __restrict__ defCnt, const int* __restrict__ defIdx,
              const unsigned* __restrict__ candCnt, const int* __restrict__ candIdx,
              const double* __restrict__ candKey, const float* __restrict__ probsT,
              float* __restrict__ out) {
  __shared__ double kd[CAP];
  __shared__ int ti[CAP];
  const int e = blockIdx.x, tid = threadIdx.x;
  const int nd = (int)defCnt[e];
  const int cnt = (int)min(candCnt[e], (unsigned)CAP);
  const int need = KSEL - nd;

  for (int i = tid; i < nd; i += 256) {
    const int t = defIdx[e * 1024 + i];
    out[(size_t)e * GS + t] = 1.0f;
    out[(size_t)MASK_ELEMS + (size_t)e * GS + t] = probsT[(size_t)e * GS + t];
  }
  for (int i = tid; i < cnt; i += 256) {
    kd[i] = candKey[e * CAP + i];
    ti[i] = candIdx[e * CAP + i];
  }
  __syncthreads();
  for (int i = tid; i < cnt; i += 256) {
    const double ki = kd[i];
    const int tii = ti[i];
    int rank = 0;
    for (int j = 0; j < cnt; ++j)
      rank += (kd[j] > ki) || (kd[j] == ki && ti[j] < tii);
    if (rank < need) {
      out[(size_t)e * GS + tii] = 1.0f;
      out[(size_t)MASK_ELEMS + (size_t)e * GS + tii] = probsT[(size_t)e * GS + tii];
    }
  }
}

extern "C" void kernel_launch(void* const* d_in, const int* in_sizes, int n_in,
                              void* d_out, int out_size, void* d_ws, size_t ws_size,
                              hipStream_t stream) {
  const float* x    = (const float*)d_in[0];
  const float* gw   = (const float*)d_in[1];
  const float* gb   = (const float*)d_in[2];
  const float* temp = (const float*)d_in[3];

  float* probsT    = (float*)d_ws;                                        // 8MB
  unsigned* ghist0 = (unsigned*)((char*)d_ws + (size_t)MASK_ELEMS * 4);   // 64KB
  unsigned* cCnt   = ghist0 + NE * 256;                                   // 256B
  unsigned* defCnt = cCnt + NE;                                           // 256B
  unsigned* candCnt = defCnt + NE;                                        // 256B
  int* defIdx      = (int*)(candCnt + NE);                                // 256KB
  int* candIdx     = defIdx + NE * 1024;                                  // 512KB
  double* candKey  = (double*)(candIdx + NE * CAP);                       // 1MB
  int* cIdx        = (int*)(candKey + NE * CAP);                          // 4MB
  float* cKey      = (float*)(cIdx + (size_t)NE * CAP2);                  // 4MB
  unsigned short* wph = (unsigned short*)(cKey + (size_t)NE * CAP2);      // 128KB
  unsigned short* wpm = wph + DM * NE;                                    // 128KB

  hipMemsetAsync(ghist0, 0, (NE * 256 + NE) * sizeof(unsigned), stream);
  hipMemsetAsync(d_out, 0, (size_t)out_size * sizeof(float), stream);
  k_split<<<DM * NE / 256, 256, 0, stream>>>(gw, wph, wpm);
  k_gemm_softmax<<<GS / 16, 128, 0, stream>>>(x, wph, wpm, gb, temp, probsT);
  k_hist0<<<NE * SEG, 256, 0, stream>>>(probsT, ghist0);
  k_compact<<<NE * SEG, 256, 0, stream>>>(probsT, ghist0, cCnt, cIdx, cKey);
  k_select2<<<NE, 256, 0, stream>>>(ghist0, cCnt, cIdx, cKey, temp, defCnt,
                                    defIdx, candCnt, candIdx);
  k_repair<<<NE * 16, 256, 0, stream>>>(x, gw, gb, temp, candCnt, candIdx, candKey);
  k_finish<<<NE, 256, 0, stream>>>(defCnt, defIdx, candCnt, candIdx, candKey,
                                   probsT, (float*)d_out);
}

// Round 17
// 107.390 us; speedup vs baseline: 1.5168x; 1.3352x over previous
//
#include <hip/hip_runtime.h>
#include <math.h>

#define NG 8
#define SEQ 4096
#define DM 1024
#define NE 64
#define GS (NG * SEQ)          // 32768 tokens
#define KSEL 1024              // expert capacity
#define MASK_ELEMS (NE * GS)   // 2097152
#define SEG 16
#define SEGLEN (GS / SEG)
#define CAP 2048               // max repair candidates per expert
#define CAP2 16384             // max compacted entries per expert
#define AST 40                 // A-plane LDS row stride in ushorts

typedef __attribute__((ext_vector_type(8))) short short8;
typedef __attribute__((ext_vector_type(4))) float f32x4;

__device__ __forceinline__ unsigned short f2bf(float v) {   // RN-even
  unsigned u = __float_as_uint(v);
  return (unsigned short)((u + 0x7FFFu + ((u >> 16) & 1u)) >> 16);
}
__device__ __forceinline__ float bf2f(unsigned short h) {
  return __uint_as_float(((unsigned)h) << 16);
}

// ---------------- Kernel 0: weight split (wave-fragment order) + counter zeroing --
// Also zeroes ghist0+cCnt (16448 dwords) -> kills one fillBuffer dispatch.
__global__ __launch_bounds__(256)
void k_split(const float* __restrict__ w, unsigned short* __restrict__ wph,
             unsigned short* __restrict__ wpm, unsigned* __restrict__ zbase) {
  const int t = blockIdx.x * 256 + threadIdx.x;
  if (t < NE * 256 + NE) zbase[t] = 0u;
  const int k = t >> 6, e = t & 63;
  float v = w[t];
  unsigned short h = f2bf(v); float r = v - bf2f(h);
  const int tile = k >> 5, g = (k >> 3) & 3, j = k & 7;
  const int cb = e >> 4, lrow = e & 15;
  const size_t o = (size_t)(tile * 4 + cb) * 512 + (g * 16 + lrow) * 8 + j;
  wph[o] = h; wpm[o] = f2bf(r);
}

// ---------------- Kernel 1: bf16x2 MFMA GEMM, K-split 2-wave blocks ---------------
// (round-17: plain loads for x — nt hint blocked L3 residency across replays;
//  x = 134MB fits the 256MB L3.)
__global__ __launch_bounds__(128, 4)
void k_gemm_softmax(const float* __restrict__ x,
                    const unsigned short* __restrict__ wph,
                    const unsigned short* __restrict__ wpm,
                    const float* __restrict__ bias, const float* __restrict__ temp,
                    float* __restrict__ probsT) {
  __shared__ __align__(16) unsigned short Ah[2][2][16 * AST], Am[2][2][16 * AST];
  __shared__ float Lt[2][16][68];
  float (*Pt)[20] = (float (*)[20])&Ah[0][0][0];   // overlay after loop

  const int tid = threadIdx.x;
  const int w = tid >> 6, lane = tid & 63;
  const int lrow = lane & 15;
  const int g = lane >> 4;
  const int m0 = blockIdx.x * 16;
  const int t0 = w * 16;

  int irow[4], jcol[4];
  {
    union { unsigned short u[8]; short8 v; } ar, on;
#pragma unroll
    for (int j = 0; j < 8; ++j) { ar.u[j] = f2bf((float)lrow); on.u[j] = 0x3F80u; }
    f32x4 z = {0.f, 0.f, 0.f, 0.f};
    f32x4 p1 = __builtin_amdgcn_mfma_f32_16x16x32_bf16(ar.v, on.v, z, 0, 0, 0);
    f32x4 p2 = __builtin_amdgcn_mfma_f32_16x16x32_bf16(on.v, ar.v, z, 0, 0, 0);
#pragma unroll
    for (int b = 0; b < 4; ++b) {
      irow[b] = ((int)p1[b]) >> 5;
      jcol[b] = ((int)p2[b]) >> 5;
    }
  }

  f32x4 acc[4];
#pragma unroll
  for (int cb = 0; cb < 4; ++cb) acc[cb] = (f32x4){0.f, 0.f, 0.f, 0.f};

  f32x4 rA0, rA1;
  short8 bhA[4], bmA[4], bhB[4], bmB[4];
  const int arow = lane >> 2, af = lane & 3;
  const int aoff = arow * AST + af * 8;
  const int foff = lrow * AST + g * 8;
  const int boff = lane * 8;

#define LOADA(t)                                                                     \
  {                                                                                  \
    const f32x4* ap = (const f32x4*)(x + (size_t)(m0 + arow) * DM + (t) * 32 + af * 8); \
    rA0 = ap[0];                                                                     \
    rA1 = ap[1];                                                                     \
  }

#define SPLITA(bi)                                                                   \
  {                                                                                  \
    union { unsigned short u[8]; short8 v; } ph, pm;                                 \
    _Pragma("unroll")                                                                \
    for (int j = 0; j < 8; ++j) {                                                    \
      float v0 = (j < 4) ? rA0[j] : rA1[j - 4];                                      \
      unsigned short h_ = f2bf(v0); float r_ = v0 - bf2f(h_);                        \
      ph.u[j] = h_; pm.u[j] = f2bf(r_);                                              \
    }                                                                                \
    *(short8*)(&Ah[w][bi][aoff]) = ph.v;                                             \
    *(short8*)(&Am[w][bi][aoff]) = pm.v;                                             \
  }

#define LOADB(t, bh, bm)                                                             \
  {                                                                                  \
    _Pragma("unroll")                                                                \
    for (int cb = 0; cb < 4; ++cb) {                                                 \
      const size_t bo = (size_t)((t) * 4 + cb) * 512 + boff;                         \
      bh[cb] = *(const short8*)(wph + bo);                                           \
      bm[cb] = *(const short8*)(wpm + bo);                                           \
    }                                                                                \
  }

#define MFMA_TILE(bi, bh, bm)                                                        \
  {                                                                                  \
    short8 ah_ = *(const short8*)(&Ah[w][bi][foff]);                                 \
    short8 am_ = *(const short8*)(&Am[w][bi][foff]);                                 \
    __builtin_amdgcn_s_setprio(1);                                                   \
    _Pragma("unroll")                                                                \
    for (int cb = 0; cb < 4; ++cb) {                                                 \
      acc[cb] = __builtin_amdgcn_mfma_f32_16x16x32_bf16(ah_, bh[cb], acc[cb], 0, 0, 0); \
      acc[cb] = __builtin_amdgcn_mfma_f32_16x16x32_bf16(am_, bh[cb], acc[cb], 0, 0, 0); \
      acc[cb] = __builtin_amdgcn_mfma_f32_16x16x32_bf16(ah_, bm[cb], acc[cb], 0, 0, 0); \
    }                                                                                \
    __builtin_amdgcn_s_setprio(0);                                                   \
  }

  LOADA(t0);
  SPLITA(0);
  LOADA(t0 + 1);
  LOADB(t0, bhA, bmA);

  for (int tt = 0; tt < 16; tt += 2) {
    LOADB(t0 + tt + 1, bhB, bmB);
    SPLITA(1);
    if (tt + 2 < 16) LOADA(t0 + tt + 2);
    MFMA_TILE(0, bhA, bmA);
    if (tt + 2 < 16) {
      LOADB(t0 + tt + 2, bhA, bmA);
      SPLITA(0);
      LOADA(t0 + tt + 3);
    }
    MFMA_TILE(1, bhB, bmB);
  }

#undef LOADA
#undef SPLITA
#undef LOADB
#undef MFMA_TILE

#pragma unroll
  for (int cb = 0; cb < 4; ++cb)
#pragma unroll
    for (int b = 0; b < 4; ++b)
      Lt[w][irow[b]][cb * 16 + jcol[b]] = acc[cb][b];
  __syncthreads();

  {
    float st = temp[0];
    if (st < 0.1f) st = 0.1f;
    const float inv_t = 1.0f / st;
    const int tk = tid >> 3, q = tid & 7;
    float l[8];
    float mx = -1.0e30f;
#pragma unroll
    for (int j = 0; j < 8; ++j) {
      const int e = q * 8 + j;
      l[j] = (Lt[0][tk][e] + Lt[1][tk][e] + bias[e]) * inv_t;
      mx = fmaxf(mx, l[j]);
    }
    mx = fmaxf(mx, __shfl_xor(mx, 1));
    mx = fmaxf(mx, __shfl_xor(mx, 2));
    mx = fmaxf(mx, __shfl_xor(mx, 4));
    float p[8], s = 0.0f;
#pragma unroll
    for (int j = 0; j < 8; ++j) { p[j] = __expf(l[j] - mx); s += p[j]; }
    s += __shfl_xor(s, 1);
    s += __shfl_xor(s, 2);
    s += __shfl_xor(s, 4);
    const float invs = 1.0f / s;
#pragma unroll
    for (int j = 0; j < 8; ++j) Pt[q * 8 + j][tk] = p[j] * invs;
  }
  __syncthreads();

  {
    const int e = tid >> 1, hf = tid & 1;
#pragma unroll
    for (int c2 = 0; c2 < 2; ++c2) {
      *(float4*)(probsT + (size_t)e * GS + m0 + hf * 8 + c2 * 4) =
          *(const float4*)(&Pt[e][hf * 8 + c2 * 4]);
    }
  }
}

// ------------- cooperative bucket pick from a 256-bin histogram (block-wide) ------
__device__ __forceinline__ void pick_scan(const unsigned* __restrict__ bins,
                                          unsigned r_in, unsigned& bucket,
                                          unsigned& r_out, unsigned* res) {
  __syncthreads();
  const int tid = threadIdx.x;
  if (tid < 64) {
    uint4 b = ((const uint4*)bins)[tid];
    unsigned s3 = b.w, s2 = b.z + s3, s1 = b.y + s2, s0 = b.x + s1;
    unsigned suf = s0;
#pragma unroll
    for (int off = 1; off < 64; off <<= 1) {
      unsigned t = __shfl_down(suf, off);
      if (tid + off < 64) suf += t;
    }
    unsigned above = suf - s0;
    unsigned inc0 = above + s0, inc1 = above + s1, inc2 = above + s2, inc3 = above + s3;
    if (inc3 >= r_in && inc3 - b.w < r_in) { res[0] = 4 * tid + 3; res[1] = r_in - (inc3 - b.w); }
    if (inc2 >= r_in && inc2 - b.z < r_in) { res[0] = 4 * tid + 2; res[1] = r_in - (inc2 - b.z); }
    if (inc1 >= r_in && inc1 - b.y < r_in) { res[0] = 4 * tid + 1; res[1] = r_in - (inc1 - b.y); }
    if (inc0 >= r_in && inc0 - b.x < r_in) { res[0] = 4 * tid + 0; res[1] = r_in - (inc0 - b.x); }
  }
  __syncthreads();
  bucket = res[0];
  r_out = res[1];
}

// ---------------- Kernel 2: pass-0 (top-byte) histogram, full scan ----------------
__global__ __launch_bounds__(256)
void k_hist0(const float* __restrict__ probsT, unsigned* __restrict__ ghist0) {
  __shared__ unsigned h[4][256];
  const int tid = threadIdx.x, wv = tid >> 6;
  const int e = blockIdx.x >> 4;
  const int seg = blockIdx.x & (SEG - 1);
  h[0][tid] = 0; h[1][tid] = 0; h[2][tid] = 0; h[3][tid] = 0;
  __syncthreads();
  const float4* col = (const float4*)(probsT + (size_t)e * GS + seg * SEGLEN);
#pragma unroll
  for (int i = 0; i < SEGLEN / 1024; ++i) {
    float4 v = col[i * 256 + tid];
    atomicAdd(&h[wv][__float_as_uint(v.x) >> 24], 1u);
    atomicAdd(&h[wv][__float_as_uint(v.y) >> 24], 1u);
    atomicAdd(&h[wv][__float_as_uint(v.z) >> 24], 1u);
    atomicAdd(&h[wv][__float_as_uint(v.w) >> 24], 1u);
  }
  __syncthreads();
  unsigned c = h[0][tid] + h[1][tid] + h[2][tid] + h[3][tid];
  if (c) atomicAdd(&ghist0[e * 256 + tid], c);
}

// ---------------- Kernel 3: compact tokens with top-byte >= b0-1 ------------------
__global__ __launch_bounds__(256)
void k_compact(const float* __restrict__ probsT, const unsigned* __restrict__ ghist0,
               unsigned* __restrict__ cCnt, int* __restrict__ cIdx,
               float* __restrict__ cKey) {
  __shared__ unsigned res[2];
  __shared__ unsigned locN, basePos;
  __shared__ int locIdx[2048];
  __shared__ float locKey[2048];
  const int tid = threadIdx.x;
  const int e = blockIdx.x >> 4;
  const int seg = blockIdx.x & (SEG - 1);

  if (tid == 0) locN = 0u;
  unsigned b0, r0;
  pick_scan(ghist0 + e * 256, KSEL, b0, r0, res);   // leading barrier covers init
  const unsigned blo = (b0 == 0u) ? 0u : (b0 - 1u);

  const float* col = probsT + (size_t)e * GS + seg * SEGLEN;
  for (int i = 0; i < SEGLEN / 256; ++i) {
    const int t = i * 256 + tid;
    const float p = col[t];
    if ((__float_as_uint(p) >> 24) >= blo) {
      unsigned pos = atomicAdd(&locN, 1u);
      locIdx[pos] = seg * SEGLEN + t;
      locKey[pos] = p;
    }
  }
  __syncthreads();
  if (tid == 0) basePos = locN ? atomicAdd(&cCnt[e], locN) : 0u;
  __syncthreads();
  const unsigned n = locN, bp = basePos;
  for (unsigned i = tid; i < n; i += 256) {
    const unsigned gp = bp + i;
    if (gp < CAP2) {
      cIdx[(size_t)e * CAP2 + gp] = locIdx[i];
      cKey[(size_t)e * CAP2 + gp] = locKey[i];
    }
  }
}

// ---------------- Kernel 4: per-expert radix passes 1-3 + classify ----------------
__global__ __launch_bounds__(256)
void k_select2(const unsigned* __restrict__ ghist0, const unsigned* __restrict__ cCnt,
               const int* __restrict__ cIdx, const float* __restrict__ cKey,
               const float* __restrict__ temp, unsigned* __restrict__ defCnt,
               unsigned* __restrict__ candCnt, int* __restrict__ candIdx,
               float* __restrict__ thrHiA) {
  __shared__ unsigned res[2];
  __shared__ unsigned h[4][256];
  __shared__ unsigned hs[256];
  __shared__ unsigned nd, nc;
  const int tid = threadIdx.x, wv = tid >> 6;
  const int e = blockIdx.x;
  const int cnt = (int)min(cCnt[e], (unsigned)CAP2);

  unsigned b0, r;
  pick_scan(ghist0 + e * 256, KSEL, b0, r, res);
  unsigned pfx = b0 << 24;

  for (int pass = 1; pass < 4; ++pass) {
    const int shift = 24 - 8 * pass;
    const unsigned hm = 0xFFFFFFFFu << (shift + 8);
    for (int i = tid; i < 1024; i += 256) ((unsigned*)h)[i] = 0u;
    __syncthreads();
    for (int i = tid; i < cnt; i += 256) {
      unsigned key = __float_as_uint(cKey[(size_t)e * CAP2 + i]);
      if ((key & hm) == (pfx & hm)) atomicAdd(&h[wv][(key >> shift) & 255], 1u);
    }
    __syncthreads();
    hs[tid] = h[0][tid] + h[1][tid] + h[2][tid] + h[3][tid];
    unsigned b, rn;
    pick_scan(hs, r, b, rn, res);
    pfx |= b << shift;
    r = rn;
  }

  const float thrv = __uint_as_float(pfx);
  float st = temp[0];
  if (st < 0.1f) st = 0.1f;
  const float rel = 2.0e-3f / st;
  const float hi = thrv * (1.0f + rel);
  const float lo = thrv * (1.0f - rel);
  if (tid == 0) thrHiA[e] = hi;

  if (tid == 0) { nd = 0u; nc = 0u; }
  __syncthreads();
  for (int i = tid; i < cnt; i += 256) {
    const float p = cKey[(size_t)e * CAP2 + i];
    const int t = cIdx[(size_t)e * CAP2 + i];
    if (p > hi) {
      atomicAdd(&nd, 1u);
    } else if (p >= lo) {
      unsigned pos = atomicAdd(&nc, 1u);
      if (pos < CAP) candIdx[e * CAP + pos] = t;
    }
  }
  __syncthreads();
  if (tid == 0) {
    defCnt[e] = nd;
    candCnt[e] = min(nc, (unsigned)CAP);
  }
}

// ---------------- Kernel 5: exact fp64 recompute of candidate probabilities -------
__global__ __launch_bounds__(256)
void k_repair(const float* __restrict__ x, const float* __restrict__ w,
              const float* __restrict__ bias, const float* __restrict__ temp,
              const unsigned* __restrict__ candCnt, const int* __restrict__ candIdx,
              double* __restrict__ candKey) {
  __shared__ double red[4][64];
  const int e = blockIdx.x >> 4;
  const int chunk = blockIdx.x & 15;
  const int tid = threadIdx.x;
  const int ee = tid & 63, q = tid >> 6;
  const int cnt = (int)min(candCnt[e], (unsigned)CAP);

  double st = (double)temp[0];
  if (st < 0.1) st = 0.1;
  const double inv_t = 1.0 / st;

  for (int i = chunk; i < cnt; i += 16) {
    const int t = candIdx[e * CAP + i];
    const float* xr = x + (size_t)t * DM;
    double s0 = 0.0, s1 = 0.0, s2 = 0.0, s3 = 0.0;
    const int kb = q * 256;
    for (int k = kb; k < kb + 256; k += 4) {
      s0 += (double)xr[k + 0] * (double)w[(size_t)(k + 0) * NE + ee];
      s1 += (double)xr[k + 1] * (double)w[(size_t)(k + 1) * NE + ee];
      s2 += (double)xr[k + 2] * (double)w[(size_t)(k + 2) * NE + ee];
      s3 += (double)xr[k + 3] * (double)w[(size_t)(k + 3) * NE + ee];
    }
    red[q][ee] = (s0 + s1) + (s2 + s3);
    __syncthreads();
    if (tid < 64) {
      double l = (red[0][tid] + red[1][tid] + red[2][tid] + red[3][tid] +
                  (double)bias[tid]) * inv_t;
      double m = l;
#pragma unroll
      for (int off = 1; off < 64; off <<= 1) m = fmax(m, __shfl_xor(m, off));
      double ex = exp(l - m);
      double ss = ex;
#pragma unroll
      for (int off = 1; off < 64; off <<= 1) ss += __shfl_xor(ss, off);
      if (tid == e) candKey[e * CAP + i] = ex / ss;
    }
    __syncthreads();
  }
}

// ---------------- Kernel 6: dense mask scatter (definite region) + loss -----------
// Replaces the d_out memset (rocclr fillBuffer measured ~40-50us for 16.8MB).
__global__ __launch_bounds__(256)
void k_scatter(const float* __restrict__ probsT, const float* __restrict__ thrHiA,
               float* __restrict__ out) {
  const int gid = blockIdx.x * 256 + threadIdx.x;
  const int base = gid * 4;
  const int e = base >> 15;
  float4 p = *(const float4*)(probsT + (size_t)base);
  const float hi = thrHiA[e];
  float pv[4] = {p.x, p.y, p.z, p.w};
  float mk[4], wt[4];
#pragma unroll
  for (int c = 0; c < 4; ++c) {
    bool sel = pv[c] > hi;
    mk[c] = sel ? 1.0f : 0.0f;
    wt[c] = sel ? pv[c] : 0.0f;
  }
  *(float4*)(out + (size_t)base) = make_float4(mk[0], mk[1], mk[2], mk[3]);
  *(float4*)(out + (size_t)MASK_ELEMS + base) = make_float4(wt[0], wt[1], wt[2], wt[3]);
  if (gid == 0) out[2 * (size_t)MASK_ELEMS] = 0.0f;
}

// ---------------- Kernel 7: rank candidates, patch selected into output -----------
__global__ __launch_bounds__(256)
void k_finish(const unsigned* __restrict__ defCnt, const unsigned* __restrict__ candCnt,
              const int* __restrict__ candIdx, const double* __restrict__ candKey,
              const float* __restrict__ probsT, float* __restrict__ out) {
  __shared__ double kd[CAP];
  __shared__ int ti[CAP];
  const int e = blockIdx.x, tid = threadIdx.x;
  const int cnt = (int)min(candCnt[e], (unsigned)CAP);
  const int need = KSEL - (int)defCnt[e];

  for (int i = tid; i < cnt; i += 256) {
    kd[i] = candKey[e * CAP + i];
    ti[i] = candIdx[e * CAP + i];
  }
  __syncthreads();
  for (int i = tid; i < cnt; i += 256) {
    const double ki = kd[i];
    const int tii = ti[i];
    int rank = 0;
    for (int j = 0; j < cnt; ++j)
      rank += (kd[j] > ki) || (kd[j] == ki && ti[j] < tii);
    if (rank < need) {
      out[(size_t)e * GS + tii] = 1.0f;
      out[(size_t)MASK_ELEMS + (size_t)e * GS + tii] = probsT[(size_t)e * GS + tii];
    }
  }
}

extern "C" void kernel_launch(void* const* d_in, const int* in_sizes, int n_in,
                              void* d_out, int out_size, void* d_ws, size_t ws_size,
                              hipStream_t stream) {
  const float* x    = (const float*)d_in[0];
  const float* gw   = (const float*)d_in[1];
  const float* gb   = (const float*)d_in[2];
  const float* temp = (const float*)d_in[3];

  float* probsT    = (float*)d_ws;                                        // 8MB
  unsigned* ghist0 = (unsigned*)((char*)d_ws + (size_t)MASK_ELEMS * 4);   // 64KB
  unsigned* cCnt   = ghist0 + NE * 256;                                   // 256B
  unsigned* defCnt = cCnt + NE;                                           // 256B
  unsigned* candCnt = defCnt + NE;                                        // 256B
  float* thrHiA    = (float*)(candCnt + NE);                              // 256B
  int* candIdx     = (int*)(thrHiA + NE);                                 // 512KB
  double* candKey  = (double*)(candIdx + NE * CAP);                       // 1MB
  int* cIdx        = (int*)(candKey + NE * CAP);                          // 4MB
  float* cKey      = (float*)(cIdx + (size_t)NE * CAP2);                  // 4MB
  unsigned short* wph = (unsigned short*)(cKey + (size_t)NE * CAP2);      // 128KB
  unsigned short* wpm = wph + DM * NE;                                    // 128KB

  k_split<<<DM * NE / 256, 256, 0, stream>>>(gw, wph, wpm, ghist0);
  k_gemm_softmax<<<GS / 16, 128, 0, stream>>>(x, wph, wpm, gb, temp, probsT);
  k_hist0<<<NE * SEG, 256, 0, stream>>>(probsT, ghist0);
  k_compact<<<NE * SEG, 256, 0, stream>>>(probsT, ghist0, cCnt, cIdx, cKey);
  k_select2<<<NE, 256, 0, stream>>>(ghist0, cCnt, cIdx, cKey, temp, defCnt,
                                    candCnt, candIdx, thrHiA);
  k_repair<<<NE * 16, 256, 0, stream>>>(x, gw, gb, temp, candCnt, candIdx, candKey);
  k_scatter<<<MASK_ELEMS / 1024, 256, 0, stream>>>(probsT, thrHiA, (float*)d_out);
  k_finish<<<NE, 256, 0, stream>>>(defCnt, candCnt, candIdx, candKey,
                                   probsT, (float*)d_out);
}

// Round 18
// 105.593 us; speedup vs baseline: 1.5427x; 1.0170x over previous
//
#include <hip/hip_runtime.h>
#include <math.h>

#define NG 8
#define SEQ 4096
#define DM 1024
#define NE 64
#define GS (NG * SEQ)          // 32768 tokens
#define KSEL 1024              // expert capacity
#define MASK_ELEMS (NE * GS)   // 2097152
#define SEG 16
#define SEGLEN (GS / SEG)
#define CAP 2048               // max repair candidates per expert
#define CAP2 16384             // max compacted entries per expert

typedef __attribute__((ext_vector_type(8))) short short8;
typedef __attribute__((ext_vector_type(4))) float f32x4;

__device__ __forceinline__ unsigned short f2bf(float v) {   // RN-even
  unsigned u = __float_as_uint(v);
  return (unsigned short)((u + 0x7FFFu + ((u >> 16) & 1u)) >> 16);
}
__device__ __forceinline__ float bf2f(unsigned short h) {
  return __uint_as_float(((unsigned)h) << 16);
}

// ---------------- Kernel 0: weight split (wave-fragment order) + counter zeroing --
__global__ __launch_bounds__(256)
void k_split(const float* __restrict__ w, unsigned short* __restrict__ wph,
             unsigned short* __restrict__ wpm, unsigned* __restrict__ zbase) {
  const int t = blockIdx.x * 256 + threadIdx.x;
  if (t < NE * 256 + NE) zbase[t] = 0u;
  const int k = t >> 6, e = t & 63;
  float v = w[t];
  unsigned short h = f2bf(v); float r = v - bf2f(h);
  const int tile = k >> 5, g = (k >> 3) & 3, j = k & 7;
  const int cb = e >> 4, lrow = e & 15;
  const size_t o = (size_t)(tile * 4 + cb) * 512 + (g * 16 + lrow) * 8 + j;
  wph[o] = h; wpm[o] = f2bf(r);
}

// ---------------- Kernel 1: bf16x2 MFMA GEMM, LDS-free K-loop, 4-way K-split ------
// Round-17 diagnosis: 12k stall-cycles/tile — compiler dismantled the B ping-pong
// (VGPR=64) and the A LDS round-trip added dependent waits. Fix: the MFMA A
// fragment (row=lane&15, k=(lane>>4)*8..+7) is 8 CONSECUTIVE floats of row-major
// x -> each lane loads it directly (2xfloat4) and splits to bf16 in registers.
// No LDS, no barriers in the K loop; 4 waves/block each own 8 k-tiles.
__global__ __launch_bounds__(256, 6)
void k_gemm_softmax(const float* __restrict__ x,
                    const unsigned short* __restrict__ wph,
                    const unsigned short* __restrict__ wpm,
                    const float* __restrict__ bias, const float* __restrict__ temp,
                    float* __restrict__ probsT) {
  __shared__ float Lt[4][16][68];                  // 17.4 KB
  float (*Pt)[20] = (float (*)[20])&Lt[0][0][0];   // overlay after epilogue barrier

  const int tid = threadIdx.x;
  const int w = tid >> 6, lane = tid & 63;
  const int lrow = lane & 15;          // A-row / B-col / D-col
  const int g = lane >> 4;             // k-slot group (8 k each)
  const int m0 = blockIdx.x * 16;
  const int t0 = w * 8;                // wave's 8 k-tiles (k in [w*256, w*256+256))

  // --- probes: C/D (lane,reg)->(i,j) for mfma_f32_16x16x32_bf16 (exact ints) ---
  int irow[4], jcol[4];
  {
    union { unsigned short u[8]; short8 v; } ar, on;
#pragma unroll
    for (int j = 0; j < 8; ++j) { ar.u[j] = f2bf((float)lrow); on.u[j] = 0x3F80u; }
    f32x4 z = {0.f, 0.f, 0.f, 0.f};
    f32x4 p1 = __builtin_amdgcn_mfma_f32_16x16x32_bf16(ar.v, on.v, z, 0, 0, 0);
    f32x4 p2 = __builtin_amdgcn_mfma_f32_16x16x32_bf16(on.v, ar.v, z, 0, 0, 0);
#pragma unroll
    for (int b = 0; b < 4; ++b) {
      irow[b] = ((int)p1[b]) >> 5;
      jcol[b] = ((int)p2[b]) >> 5;
    }
  }

  f32x4 acc[4];
#pragma unroll
  for (int cb = 0; cb < 4; ++cb) acc[cb] = (f32x4){0.f, 0.f, 0.f, 0.f};

  const float* aptr = x + (size_t)(m0 + lrow) * DM + g * 8;
  const int boff = lane * 8;

  for (int t = t0; t < t0 + 8; ++t) {
    // B fragments: 8 x 1KB-contiguous wave loads (fragment-order planes)
    short8 bh[4], bm[4];
#pragma unroll
    for (int cb = 0; cb < 4; ++cb) {
      const size_t bo = (size_t)(t * 4 + cb) * 512 + boff;
      bh[cb] = *(const short8*)(wph + bo);
      bm[cb] = *(const short8*)(wpm + bo);
    }
    // A fragment: 8 consecutive floats, direct from global
    f32x4 a0 = *(const f32x4*)(aptr + t * 32);
    f32x4 a1 = *(const f32x4*)(aptr + t * 32 + 4);
    union { unsigned short u[8]; short8 v; } ah, am;
#pragma unroll
    for (int j = 0; j < 8; ++j) {
      float v0 = (j < 4) ? a0[j] : a1[j - 4];
      unsigned short h_ = f2bf(v0);
      ah.u[j] = h_; am.u[j] = f2bf(v0 - bf2f(h_));
    }
    __builtin_amdgcn_s_setprio(1);
#pragma unroll
    for (int cb = 0; cb < 4; ++cb) {
      acc[cb] = __builtin_amdgcn_mfma_f32_16x16x32_bf16(ah.v, bh[cb], acc[cb], 0, 0, 0);
      acc[cb] = __builtin_amdgcn_mfma_f32_16x16x32_bf16(am.v, bh[cb], acc[cb], 0, 0, 0);
      acc[cb] = __builtin_amdgcn_mfma_f32_16x16x32_bf16(ah.v, bm[cb], acc[cb], 0, 0, 0);
    }
    __builtin_amdgcn_s_setprio(0);
  }

  // --- per-wave partial logits into Lt[w] via probe-measured mapping ---
#pragma unroll
  for (int cb = 0; cb < 4; ++cb)
#pragma unroll
    for (int b = 0; b < 4; ++b)
      Lt[w][irow[b]][cb * 16 + jcol[b]] = acc[cb][b];
  __syncthreads();

  // --- fused fp32 softmax: 16 threads per token, 4 experts each ---
  float pr[4];
  int tk, q;
  {
    float st = temp[0];
    if (st < 0.1f) st = 0.1f;
    const float inv_t = 1.0f / st;
    tk = tid >> 4; q = tid & 15;
    float l[4];
    float mx = -1.0e30f;
#pragma unroll
    for (int j = 0; j < 4; ++j) {
      const int e = q * 4 + j;
      l[j] = (Lt[0][tk][e] + Lt[1][tk][e] + Lt[2][tk][e] + Lt[3][tk][e] + bias[e]) *
             inv_t;
      mx = fmaxf(mx, l[j]);
    }
    mx = fmaxf(mx, __shfl_xor(mx, 1));
    mx = fmaxf(mx, __shfl_xor(mx, 2));
    mx = fmaxf(mx, __shfl_xor(mx, 4));
    mx = fmaxf(mx, __shfl_xor(mx, 8));
    float p[4], s = 0.0f;
#pragma unroll
    for (int j = 0; j < 4; ++j) { p[j] = __expf(l[j] - mx); s += p[j]; }
    s += __shfl_xor(s, 1);
    s += __shfl_xor(s, 2);
    s += __shfl_xor(s, 4);
    s += __shfl_xor(s, 8);
    const float invs = 1.0f / s;
#pragma unroll
    for (int j = 0; j < 4; ++j) pr[j] = p[j] * invs;
  }
  __syncthreads();   // all Lt reads complete before Pt overlay
#pragma unroll
  for (int j = 0; j < 4; ++j) Pt[q * 4 + j][tk] = pr[j];
  __syncthreads();

  // --- expert-major store: 4 threads per expert, float4 each ---
  {
    const int e = tid >> 2, qq = tid & 3;
    *(float4*)(probsT + (size_t)e * GS + m0 + qq * 4) =
        *(const float4*)(&Pt[e][qq * 4]);
  }
}

// ------------- cooperative bucket pick from a 256-bin histogram (block-wide) ------
__device__ __forceinline__ void pick_scan(const unsigned* __restrict__ bins,
                                          unsigned r_in, unsigned& bucket,
                                          unsigned& r_out, unsigned* res) {
  __syncthreads();
  const int tid = threadIdx.x;
  if (tid < 64) {
    uint4 b = ((const uint4*)bins)[tid];
    unsigned s3 = b.w, s2 = b.z + s3, s1 = b.y + s2, s0 = b.x + s1;
    unsigned suf = s0;
#pragma unroll
    for (int off = 1; off < 64; off <<= 1) {
      unsigned t = __shfl_down(suf, off);
      if (tid + off < 64) suf += t;
    }
    unsigned above = suf - s0;
    unsigned inc0 = above + s0, inc1 = above + s1, inc2 = above + s2, inc3 = above + s3;
    if (inc3 >= r_in && inc3 - b.w < r_in) { res[0] = 4 * tid + 3; res[1] = r_in - (inc3 - b.w); }
    if (inc2 >= r_in && inc2 - b.z < r_in) { res[0] = 4 * tid + 2; res[1] = r_in - (inc2 - b.z); }
    if (inc1 >= r_in && inc1 - b.y < r_in) { res[0] = 4 * tid + 1; res[1] = r_in - (inc1 - b.y); }
    if (inc0 >= r_in && inc0 - b.x < r_in) { res[0] = 4 * tid + 0; res[1] = r_in - (inc0 - b.x); }
  }
  __syncthreads();
  bucket = res[0];
  r_out = res[1];
}

// ---------------- Kernel 2: pass-0 (top-byte) histogram, full scan ----------------
__global__ __launch_bounds__(256)
void k_hist0(const float* __restrict__ probsT, unsigned* __restrict__ ghist0) {
  __shared__ unsigned h[4][256];
  const int tid = threadIdx.x, wv = tid >> 6;
  const int e = blockIdx.x >> 4;
  const int seg = blockIdx.x & (SEG - 1);
  h[0][tid] = 0; h[1][tid] = 0; h[2][tid] = 0; h[3][tid] = 0;
  __syncthreads();
  const float4* col = (const float4*)(probsT + (size_t)e * GS + seg * SEGLEN);
#pragma unroll
  for (int i = 0; i < SEGLEN / 1024; ++i) {
    float4 v = col[i * 256 + tid];
    atomicAdd(&h[wv][__float_as_uint(v.x) >> 24], 1u);
    atomicAdd(&h[wv][__float_as_uint(v.y) >> 24], 1u);
    atomicAdd(&h[wv][__float_as_uint(v.z) >> 24], 1u);
    atomicAdd(&h[wv][__float_as_uint(v.w) >> 24], 1u);
  }
  __syncthreads();
  unsigned c = h[0][tid] + h[1][tid] + h[2][tid] + h[3][tid];
  if (c) atomicAdd(&ghist0[e * 256 + tid], c);
}

// ---------------- Kernel 3: compact tokens with top-byte >= b0-1 ------------------
__global__ __launch_bounds__(256)
void k_compact(const float* __restrict__ probsT, const unsigned* __restrict__ ghist0,
               unsigned* __restrict__ cCnt, int* __restrict__ cIdx,
               float* __restrict__ cKey) {
  __shared__ unsigned res[2];
  __shared__ unsigned locN, basePos;
  __shared__ int locIdx[2048];
  __shared__ float locKey[2048];
  const int tid = threadIdx.x;
  const int e = blockIdx.x >> 4;
  const int seg = blockIdx.x & (SEG - 1);

  if (tid == 0) locN = 0u;
  unsigned b0, r0;
  pick_scan(ghist0 + e * 256, KSEL, b0, r0, res);
  const unsigned blo = (b0 == 0u) ? 0u : (b0 - 1u);

  const float* col = probsT + (size_t)e * GS + seg * SEGLEN;
  for (int i = 0; i < SEGLEN / 256; ++i) {
    const int t = i * 256 + tid;
    const float p = col[t];
    if ((__float_as_uint(p) >> 24) >= blo) {
      unsigned pos = atomicAdd(&locN, 1u);
      locIdx[pos] = seg * SEGLEN + t;
      locKey[pos] = p;
    }
  }
  __syncthreads();
  if (tid == 0) basePos = locN ? atomicAdd(&cCnt[e], locN) : 0u;
  __syncthreads();
  const unsigned n = locN, bp = basePos;
  for (unsigned i = tid; i < n; i += 256) {
    const unsigned gp = bp + i;
    if (gp < CAP2) {
      cIdx[(size_t)e * CAP2 + gp] = locIdx[i];
      cKey[(size_t)e * CAP2 + gp] = locKey[i];
    }
  }
}

// ---------------- Kernel 4: per-expert radix passes 1-3 + classify ----------------
__global__ __launch_bounds__(256)
void k_select2(const unsigned* __restrict__ ghist0, const unsigned* __restrict__ cCnt,
               const int* __restrict__ cIdx, const float* __restrict__ cKey,
               const float* __restrict__ temp, unsigned* __restrict__ defCnt,
               unsigned* __restrict__ candCnt, int* __restrict__ candIdx,
               float* __restrict__ thrHiA) {
  __shared__ unsigned res[2];
  __shared__ unsigned h[4][256];
  __shared__ unsigned hs[256];
  __shared__ unsigned nd, nc;
  const int tid = threadIdx.x, wv = tid >> 6;
  const int e = blockIdx.x;
  const int cnt = (int)min(cCnt[e], (unsigned)CAP2);

  unsigned b0, r;
  pick_scan(ghist0 + e * 256, KSEL, b0, r, res);
  unsigned pfx = b0 << 24;

  for (int pass = 1; pass < 4; ++pass) {
    const int shift = 24 - 8 * pass;
    const unsigned hm = 0xFFFFFFFFu << (shift + 8);
    for (int i = tid; i < 1024; i += 256) ((unsigned*)h)[i] = 0u;
    __syncthreads();
    for (int i = tid; i < cnt; i += 256) {
      unsigned key = __float_as_uint(cKey[(size_t)e * CAP2 + i]);
      if ((key & hm) == (pfx & hm)) atomicAdd(&h[wv][(key >> shift) & 255], 1u);
    }
    __syncthreads();
    hs[tid] = h[0][tid] + h[1][tid] + h[2][tid] + h[3][tid];
    unsigned b, rn;
    pick_scan(hs, r, b, rn, res);
    pfx |= b << shift;
    r = rn;
  }

  const float thrv = __uint_as_float(pfx);
  float st = temp[0];
  if (st < 0.1f) st = 0.1f;
  const float rel = 2.0e-3f / st;
  const float hi = thrv * (1.0f + rel);
  const float lo = thrv * (1.0f - rel);
  if (tid == 0) thrHiA[e] = hi;

  if (tid == 0) { nd = 0u; nc = 0u; }
  __syncthreads();
  for (int i = tid; i < cnt; i += 256) {
    const float p = cKey[(size_t)e * CAP2 + i];
    const int t = cIdx[(size_t)e * CAP2 + i];
    if (p > hi) {
      atomicAdd(&nd, 1u);
    } else if (p >= lo) {
      unsigned pos = atomicAdd(&nc, 1u);
      if (pos < CAP) candIdx[e * CAP + pos] = t;
    }
  }
  __syncthreads();
  if (tid == 0) {
    defCnt[e] = nd;
    candCnt[e] = min(nc, (unsigned)CAP);
  }
}

// ---------------- Kernel 5: exact fp64 recompute of candidate probabilities -------
__global__ __launch_bounds__(256)
void k_repair(const float* __restrict__ x, const float* __restrict__ w,
              const float* __restrict__ bias, const float* __restrict__ temp,
              const unsigned* __restrict__ candCnt, const int* __restrict__ candIdx,
              double* __restrict__ candKey) {
  __shared__ double red[4][64];
  const int e = blockIdx.x >> 4;
  const int chunk = blockIdx.x & 15;
  const int tid = threadIdx.x;
  const int ee = tid & 63, q = tid >> 6;
  const int cnt = (int)min(candCnt[e], (unsigned)CAP);

  double st = (double)temp[0];
  if (st < 0.1) st = 0.1;
  const double inv_t = 1.0 / st;

  for (int i = chunk; i < cnt; i += 16) {
    const int t = candIdx[e * CAP + i];
    const float* xr = x + (size_t)t * DM;
    double s0 = 0.0, s1 = 0.0, s2 = 0.0, s3 = 0.0;
    const int kb = q * 256;
    for (int k = kb; k < kb + 256; k += 4) {
      s0 += (double)xr[k + 0] * (double)w[(size_t)(k + 0) * NE + ee];
      s1 += (double)xr[k + 1] * (double)w[(size_t)(k + 1) * NE + ee];
      s2 += (double)xr[k + 2] * (double)w[(size_t)(k + 2) * NE + ee];
      s3 += (double)xr[k + 3] * (double)w[(size_t)(k + 3) * NE + ee];
    }
    red[q][ee] = (s0 + s1) + (s2 + s3);
    __syncthreads();
    if (tid < 64) {
      double l = (red[0][tid] + red[1][tid] + red[2][tid] + red[3][tid] +
                  (double)bias[tid]) * inv_t;
      double m = l;
#pragma unroll
      for (int off = 1; off < 64; off <<= 1) m = fmax(m, __shfl_xor(m, off));
      double ex = exp(l - m);
      double ss = ex;
#pragma unroll
      for (int off = 1; off < 64; off <<= 1) ss += __shfl_xor(ss, off);
      if (tid == e) candKey[e * CAP + i] = ex / ss;
    }
    __syncthreads();
  }
}

// ---------------- Kernel 6: dense mask scatter (definite region) + loss -----------
__global__ __launch_bounds__(256)
void k_scatter(const float* __restrict__ probsT, const float* __restrict__ thrHiA,
               float* __restrict__ out) {
  const int gid = blockIdx.x * 256 + threadIdx.x;
  const int base = gid * 4;
  const int e = base >> 15;
  float4 p = *(const float4*)(probsT + (size_t)base);
  const float hi = thrHiA[e];
  float pv[4] = {p.x, p.y, p.z, p.w};
  float mk[4], wt[4];
#pragma unroll
  for (int c = 0; c < 4; ++c) {
    bool sel = pv[c] > hi;
    mk[c] = sel ? 1.0f : 0.0f;
    wt[c] = sel ? pv[c] : 0.0f;
  }
  *(float4*)(out + (size_t)base) = make_float4(mk[0], mk[1], mk[2], mk[3]);
  *(float4*)(out + (size_t)MASK_ELEMS + base) = make_float4(wt[0], wt[1], wt[2], wt[3]);
  if (gid == 0) out[2 * (size_t)MASK_ELEMS] = 0.0f;
}

// ---------------- Kernel 7: rank candidates, patch selected into output -----------
__global__ __launch_bounds__(256)
void k_finish(const unsigned* __restrict__ defCnt, const unsigned* __restrict__ candCnt,
              const int* __restrict__ candIdx, const double* __restrict__ candKey,
              const float* __restrict__ probsT, float* __restrict__ out) {
  __shared__ double kd[CAP];
  __shared__ int ti[CAP];
  const int e = blockIdx.x, tid = threadIdx.x;
  const int cnt = (int)min(candCnt[e], (unsigned)CAP);
  const int need = KSEL - (int)defCnt[e];

  for (int i = tid; i < cnt; i += 256) {
    kd[i] = candKey[e * CAP + i];
    ti[i] = candIdx[e * CAP + i];
  }
  __syncthreads();
  for (int i = tid; i < cnt; i += 256) {
    const double ki = kd[i];
    const int tii = ti[i];
    int rank = 0;
    for (int j = 0; j < cnt; ++j)
      rank += (kd[j] > ki) || (kd[j] == ki && ti[j] < tii);
    if (rank < need) {
      out[(size_t)e * GS + tii] = 1.0f;
      out[(size_t)MASK_ELEMS + (size_t)e * GS + tii] = probsT[(size_t)e * GS + tii];
    }
  }
}

extern "C" void kernel_launch(void* const* d_in, const int* in_sizes, int n_in,
                              void* d_out, int out_size, void* d_ws, size_t ws_size,
                              hipStream_t stream) {
  const float* x    = (const float*)d_in[0];
  const float* gw   = (const float*)d_in[1];
  const float* gb   = (const float*)d_in[2];
  const float* temp = (const float*)d_in[3];

  float* probsT    = (float*)d_ws;                                        // 8MB
  unsigned* ghist0 = (unsigned*)((char*)d_ws + (size_t)MASK_ELEMS * 4);   // 64KB
  unsigned* cCnt   = ghist0 + NE * 256;                                   // 256B
  unsigned* defCnt = cCnt + NE;                                           // 256B
  unsigned* candCnt = defCnt + NE;                                        // 256B
  float* thrHiA    = (float*)(candCnt + NE);                              // 256B
  int* candIdx     = (int*)(thrHiA + NE);                                 // 512KB
  double* candKey  = (double*)(candIdx + NE * CAP);                       // 1MB
  int* cIdx        = (int*)(candKey + NE * CAP);                          // 4MB
  float* cKey      = (float*)(cIdx + (size_t)NE * CAP2);                  // 4MB
  unsigned short* wph = (unsigned short*)(cKey + (size_t)NE * CAP2);      // 128KB
  unsigned short* wpm = wph + DM * NE;                                    // 128KB

  k_split<<<DM * NE / 256, 256, 0, stream>>>(gw, wph, wpm, ghist0);
  k_gemm_softmax<<<GS / 16, 256, 0, stream>>>(x, wph, wpm, gb, temp, probsT);
  k_hist0<<<NE * SEG, 256, 0, stream>>>(probsT, ghist0);
  k_compact<<<NE * SEG, 256, 0, stream>>>(probsT, ghist0, cCnt, cIdx, cKey);
  k_select2<<<NE, 256, 0, stream>>>(ghist0, cCnt, cIdx, cKey, temp, defCnt,
                                    candCnt, candIdx, thrHiA);
  k_repair<<<NE * 16, 256, 0, stream>>>(x, gw, gb, temp, candCnt, candIdx, candKey);
  k_scatter<<<MASK_ELEMS / 1024, 256, 0, stream>>>(probsT, thrHiA, (float*)d_out);
  k_finish<<<NE, 256, 0, stream>>>(defCnt, candCnt, candIdx, candKey,
                                   probsT, (float*)d_out);
}